// Round 1
// baseline (112.000 us; speedup 1.0000x reference)
//
#include <hip/hip_runtime.h>

#define B 8
#define L 512
#define D 256
#define U 32
#define ST 16         // queries per attn block = MFMA M
#define QKR 8         // rows per qk block

#define K2E    2.885390081777927f    // 2*log2(e)
#define KLOG2E 1.4426950408889634f   // log2(e)

typedef __attribute__((ext_vector_type(8))) _Float16 half8;
typedef __attribute__((ext_vector_type(4))) float    float4v;

// ---------------------------------------------------------------------------
// qk: Eq[row,u] = exp2(K2E*(x Wt + bh));  Ek[row,u] = exp2(K2E*(x Wx));
// also emits xT[b][d][t] fp16 (B^T layout for the attn MFMA).
// grid 512, 256 thr = (dq:4)x(r:8)x(g:8). XCD swizzle: b = blk&7.
// exp2 hoist: tanh(q+k) = 1 - 2/(Eq*Ek+1) — moves 67M exp2 out of attn.
// ---------------------------------------------------------------------------
__global__ __launch_bounds__(256) void qk_kernel(
    const float* __restrict__ x,
    const float* __restrict__ Wt,
    const float* __restrict__ Wx,
    const float* __restrict__ bh,
    float* __restrict__ Eq,
    float* __restrict__ Ek,
    _Float16* __restrict__ xT)
{
    __shared__ float  xs[QKR][D + 1];
    __shared__ float4 pq[3][QKR][8];
    __shared__ float4 pk[3][QKR][8];

    const int b    = blockIdx.x & 7;       // XCD swizzle
    const int tile = blockIdx.x >> 3;
    const int row0 = b * L + tile * QKR;
    const int tid  = threadIdx.x;

    const float4* xg = (const float4*)(x + row0 * D);
    #pragma unroll
    for (int i = tid; i < QKR * D / 4; i += 256) {
        float4 v = xg[i];
        int r = i >> 6;
        int c = (i & 63) << 2;
        xs[r][c] = v.x; xs[r][c + 1] = v.y; xs[r][c + 2] = v.z; xs[r][c + 3] = v.w;
    }
    __syncthreads();

    // emit xT fp16: thread d=tid writes its 8-row t-slice (16 B store)
    {
        const int d = tid;
        half8 h;
        #pragma unroll
        for (int r = 0; r < QKR; ++r) h[r] = (_Float16)xs[r][d];
        *(half8*)(xT + (b * D + d) * L + tile * QKR) = h;
    }

    const int dq = tid >> 6;
    const int r  = (tid >> 3) & 7;
    const int g  = tid & 7;
    const float4* __restrict__ Wt4 = (const float4*)Wt;
    const float4* __restrict__ Wx4 = (const float4*)Wx;

    float4 qa = {0.f, 0.f, 0.f, 0.f};
    float4 ka = {0.f, 0.f, 0.f, 0.f};
    const int d0 = dq * (D / 4);
    #pragma unroll 8
    for (int dd = 0; dd < D / 4; ++dd) {
        const int d = d0 + dd;
        float  xv = xs[r][d];
        float4 wt = Wt4[d * 8 + g];
        float4 wx = Wx4[d * 8 + g];
        qa.x = fmaf(xv, wt.x, qa.x); qa.y = fmaf(xv, wt.y, qa.y);
        qa.z = fmaf(xv, wt.z, qa.z); qa.w = fmaf(xv, wt.w, qa.w);
        ka.x = fmaf(xv, wx.x, ka.x); ka.y = fmaf(xv, wx.y, ka.y);
        ka.z = fmaf(xv, wx.z, ka.z); ka.w = fmaf(xv, wx.w, ka.w);
    }

    if (dq > 0) { pq[dq - 1][r][g] = qa; pk[dq - 1][r][g] = ka; }
    __syncthreads();
    if (dq == 0) {
        #pragma unroll
        for (int w = 0; w < 3; ++w) {
            float4 a = pq[w][r][g], c = pk[w][r][g];
            qa.x += a.x; qa.y += a.y; qa.z += a.z; qa.w += a.w;
            ka.x += c.x; ka.y += c.y; ka.z += c.z; ka.w += c.w;
        }
        float4 b4 = ((const float4*)bh)[g];
        qa.x = __builtin_amdgcn_exp2f((qa.x + b4.x) * K2E);
        qa.y = __builtin_amdgcn_exp2f((qa.y + b4.y) * K2E);
        qa.z = __builtin_amdgcn_exp2f((qa.z + b4.z) * K2E);
        qa.w = __builtin_amdgcn_exp2f((qa.w + b4.w) * K2E);
        ka.x = __builtin_amdgcn_exp2f(ka.x * K2E);
        ka.y = __builtin_amdgcn_exp2f(ka.y * K2E);
        ka.z = __builtin_amdgcn_exp2f(ka.z * K2E);
        ka.w = __builtin_amdgcn_exp2f(ka.w * K2E);
        const int row = row0 + r;
        ((float4*)Eq)[row * 8 + g] = qa;
        ((float4*)Ek)[row * 8 + g] = ka;
    }
}

// ---------------------------------------------------------------------------
// attn: one block per (b, 16-query tile). 1024 threads = 16 waves.
// thread (t = tid&511, half sh = tid>>9) owns key t for 8 of the 16 s.
// No max-reduction: alpha is bounded by sum|Wa| (~6.3), so exp2(log2e*alpha)
// is in [2^-10, 2^10] — safely inside fp16 normal range.
// Part A uses PAIRWISE rcp combining:
//   Wa1/a + Wa2/b = (Wa1*b + Wa2*a) * rcp(a*b)
// halving transcendental-pipe pressure (the binding pipe), and splits the
// accumulator into two chains to cut serial fma dependency depth 32->8.
// Part C: wave wv does MFMA on d-strip [wv*16, wv*16+16).
// ---------------------------------------------------------------------------
__global__ __launch_bounds__(1024) void attn_kernel(
    const _Float16* __restrict__ xT,
    const float* __restrict__ Eq,
    const float* __restrict__ Ek,
    const float* __restrict__ Wa,
    const float* __restrict__ ba,
    float* __restrict__ out)
{
    const int blk = blockIdx.x;          // grid = 256
    const int b   = blk & 7;             // XCD swizzle
    const int s0  = (blk >> 3) * ST;
    const int tid = threadIdx.x;
    const int wv  = tid >> 6;            // 0..15
    const int ln  = tid & 63;
    const int t   = tid & 511;
    const int sh  = tid >> 9;            // 0/1: which 8 of the 16 queries

    __shared__ _Float16 a_sh[ST][L + 8]; // rows 1040 B (16B-aligned)
    __shared__ float inv_sh[ST];

    // ---- per-thread Ek row (t) ----
    float ek[U];
    {
        const float4* k4 = (const float4*)(Ek + (b * L + t) * U);
        #pragma unroll
        for (int c = 0; c < 8; ++c) {
            float4 v = k4[c];
            ek[4*c] = v.x; ek[4*c+1] = v.y; ek[4*c+2] = v.z; ek[4*c+3] = v.w;
        }
    }
    float sWa = 0.f;
    #pragma unroll
    for (int u = 0; u < U; ++u) sWa += Wa[u];          // s_loads
    const float base = (sWa + ba[0]) * KLOG2E;

    // ---- part A: alphaK = base - 2log2e * Sum_u Wa_u / (Eq_su*Ek_tu + 1) ----
    // pairwise: Wa1/a + Wa2/b = (Wa1*b + Wa2*a) * rcp(a*b); a,b <= ~5e8 so
    // a*b <= ~2.4e17 — no f32 overflow; shared-rcp rel err ~1e-7, negligible.
    const float* __restrict__ eqrow = Eq + (b * L + s0 + sh * 8) * U;
    #pragma unroll 1
    for (int s = 0; s < 8; ++s) {
        const float* __restrict__ q = eqrow + s * U;   // s_load (uniform)
        float acc0 = 0.f, acc1 = 0.f;
        #pragma unroll
        for (int p = 0; p < U / 2; ++p) {
            float a  = fmaf(q[2*p],     ek[2*p],     1.f);
            float bb = fmaf(q[2*p + 1], ek[2*p + 1], 1.f);
            float n  = Wa[2*p] * bb;                   // Wa: SGPR operands
            n        = fmaf(Wa[2*p + 1], a, n);
            float r  = __builtin_amdgcn_rcpf(a * bb);  // 1 rcp per 2 u
            if (p & 1) acc1 = fmaf(n, r, acc1);
            else       acc0 = fmaf(n, r, acc0);
        }
        float avK = fmaf(acc0 + acc1, -2.f * KLOG2E, base);
        a_sh[sh * 8 + s][t] = (_Float16)__builtin_amdgcn_exp2f(avK);
    }
    __syncthreads();

    // ---- part B: wave wv sums softmax row wv (512 fp16 = 8/lane) ----
    {
        half8 h = *(const half8*)&a_sh[wv][ln * 8];
        float ss = 0.f;
        #pragma unroll
        for (int i = 0; i < 8; ++i) ss += (float)h[i];
        #pragma unroll
        for (int off = 1; off < 64; off <<= 1) ss += __shfl_xor(ss, off);
        if (ln == 0) inv_sh[wv] = __builtin_amdgcn_rcpf(ss);
    }
    __syncthreads();

    // ---- part C: MFMA  C[16 s][16 d-strip] over K=512 ----
    const int n0   = wv * 16;
    const int row  = ln & 15;            // A row (s) == B^T row (d)
    const int quad = ln >> 4;
    const _Float16* __restrict__ xrow = xT + (b * D + n0 + row) * L + quad * 8;
    const _Float16* __restrict__ arow = &a_sh[row][quad * 8];

    float4v acc = {0.f, 0.f, 0.f, 0.f};
    #pragma unroll 4
    for (int kc = 0; kc < 16; ++kc) {
        half8 af = *(const half8*)(arow + kc * 32);
        half8 bf = *(const half8*)(xrow + kc * 32);
        acc = __builtin_amdgcn_mfma_f32_16x16x32_f16(af, bf, acc, 0, 0, 0);
    }

    // epilogue: C row m = quad*4+r (s), col = row (d); scale by inv[s]
    #pragma unroll
    for (int r = 0; r < 4; ++r) {
        const int m = quad * 4 + r;
        out[(b * L + s0 + m) * D + n0 + row] = acc[r] * inv_sh[m];
    }
}

extern "C" void kernel_launch(void* const* d_in, const int* in_sizes, int n_in,
                              void* d_out, int out_size, void* d_ws, size_t ws_size,
                              hipStream_t stream)
{
    const float* x  = (const float*)d_in[0];
    const float* Wt = (const float*)d_in[1];
    const float* Wx = (const float*)d_in[2];
    const float* bh = (const float*)d_in[3];
    const float* Wa = (const float*)d_in[4];
    const float* ba = (const float*)d_in[5];
    float* out = (float*)d_out;

    float*    Eq = (float*)d_ws;                 // B*L*U floats (512 KB)
    float*    Ek = Eq + B * L * U;               // B*L*U floats (512 KB)
    _Float16* xT = (_Float16*)(Ek + B * L * U);  // B*D*L fp16   (2 MB)

    qk_kernel<<<B * L / QKR, 256, 0, stream>>>(x, Wt, Wx, bh, Eq, Ek, xT);
    attn_kernel<<<B * (L / ST), 1024, 0, stream>>>(xT, Eq, Ek, Wa, ba, out);
}